// Round 1
// baseline (288.344 us; speedup 1.0000x reference)
//
#include <hip/hip_runtime.h>

#define N_NODES 50000
#define N_EDGES 800000
#define R_REL   8
#define NR      (N_NODES * R_REL)        // 400000

// bucketed CSR build
#define NBKT    196                      // buckets of 256 dst-nodes
#define BNSH    8                        // dst>>8 -> bucket
#define BKEYS   2048                     // keys per bucket (256 nodes x 8 rels)
#define BCAP    5120                     // record capacity per bucket (mean 4083, +16 sigma)
#define SLAB    2048                     // edges per bin-block
#define BINBLK  ((N_EDGES + SLAB - 1) / SLAB)  // 391

typedef float  f32x4  __attribute__((ext_vector_type(4)));
typedef __bf16 bf16x8 __attribute__((ext_vector_type(8)));

__device__ __forceinline__ unsigned short f2bf(float f) {
    unsigned int u = __float_as_uint(f);
    u = (u + 0x7FFFu + ((u >> 16) & 1u)) >> 16;   // RNE
    return (unsigned short)u;
}
__device__ __forceinline__ float bflo(unsigned int u) { return __uint_as_float(u << 16); }
__device__ __forceinline__ float bfhi(unsigned int u) { return __uint_as_float(u & 0xFFFF0000u); }

__device__ __forceinline__ void acc16(float* a, uint4 u0, uint4 u1) {
    a[0]  += bflo(u0.x);   a[1]  += bfhi(u0.x);
    a[2]  += bflo(u0.y);   a[3]  += bfhi(u0.y);
    a[4]  += bflo(u0.z);   a[5]  += bfhi(u0.z);
    a[6]  += bflo(u0.w);   a[7]  += bfhi(u0.w);
    a[8]  += bflo(u1.x);   a[9]  += bfhi(u1.x);
    a[10] += bflo(u1.y);   a[11] += bfhi(u1.y);
    a[12] += bflo(u1.z);   a[13] += bfhi(u1.z);
    a[14] += bflo(u1.w);   a[15] += bfhi(u1.w);
}

// ---------------- bucketed CSR build ----------------

__global__ __launch_bounds__(256) void k_binA(
    const int* __restrict__ src, const int* __restrict__ dst,
    const int* __restrict__ et, int* __restrict__ gcur,
    uint2* __restrict__ gbin)
{
    __shared__ int hist[NBKT];
    __shared__ int base[NBKT];
    const int t = threadIdx.x;
    const int e0 = blockIdx.x * SLAB;
    for (int i = t; i < NBKT; i += 256) hist[i] = 0;
    __syncthreads();
#pragma unroll
    for (int i = 0; i < SLAB / 256; ++i) {
        int e = e0 + i * 256 + t;
        if (e < N_EDGES) atomicAdd(&hist[dst[e] >> BNSH], 1);
    }
    __syncthreads();
    for (int i = t; i < NBKT; i += 256) {
        int h = hist[i];
        base[i] = (h > 0) ? atomicAdd(&gcur[i], h) : 0;
        hist[i] = 0;   // reuse as sub-cursor
    }
    __syncthreads();
#pragma unroll
    for (int i = 0; i < SLAB / 256; ++i) {
        int e = e0 + i * 256 + t;
        if (e < N_EDGES) {
            int d = dst[e];
            int b = d >> BNSH;
            int sub = atomicAdd(&hist[b], 1);
            gbin[b * BCAP + base[b] + sub] =
                make_uint2((unsigned)src[e], (unsigned)(d * 8 + et[e]));
        }
    }
}

// count + in-block exclusive scan (bucket b's 2048 keys == scan chunk b).
// Writes PARTIAL offs (missing inter-bucket prefix) + bsum[b] = bucket total.
__global__ __launch_bounds__(256) void k_bcount_scan(
    const int* __restrict__ gcur, const uint2* __restrict__ gbin,
    int* __restrict__ offs, int* __restrict__ bsum)
{
    __shared__ int lc[BKEYS];
    __shared__ int sd[256];
    const int t = threadIdx.x;
    const int b = blockIdx.x;
    for (int i = t; i < BKEYS; i += 256) lc[i] = 0;
    __syncthreads();
    const int n = gcur[b];
    const uint2* rec = gbin + (size_t)b * BCAP;
    const int kbase = b * BKEYS;
    for (int j = t; j < n; j += 256)
        atomicAdd(&lc[rec[j].y - kbase], 1);
    __syncthreads();
    // 8-per-thread serial scan + 256-wide block scan
    const int base = t * 8;
    int v[8];
    int tot = 0;
#pragma unroll
    for (int i = 0; i < 8; i++) {
        int xv = lc[base + i];
        v[i] = tot;
        tot += xv;
    }
    sd[t] = tot;
    __syncthreads();
    for (int off = 1; off < 256; off <<= 1) {
        int y = (t >= off) ? sd[t - off] : 0;
        __syncthreads();
        sd[t] += y;
        __syncthreads();
    }
    int excl = sd[t] - tot;
#pragma unroll
    for (int i = 0; i < 8; i++) {
        int k = kbase + base + i;
        if (k < NR) offs[k] = v[i] + excl;
    }
    if (t == 255) bsum[b] = sd[255];
}

// inline 196-entry scan of bsum (every block redoes it, trivial) ->
// finalize this bucket's offs slice -> scatter srcS from LDS bases.
__global__ __launch_bounds__(256) void k_bscat_final(
    const int* __restrict__ gcur, const uint2* __restrict__ gbin,
    const int* __restrict__ bsum, int* __restrict__ offs,
    int* __restrict__ srcS)
{
    __shared__ int obase[BKEYS];
    __shared__ int cur[BKEYS];
    __shared__ int sd[256];
    __shared__ int sadd;
    const int t = threadIdx.x;
    const int b = blockIdx.x;

    int v = (t < NBKT) ? bsum[t] : 0;
    sd[t] = v;
    __syncthreads();
    for (int off = 1; off < 256; off <<= 1) {
        int y = (t >= off) ? sd[t - off] : 0;
        __syncthreads();
        sd[t] += y;
        __syncthreads();
    }
    if (t == b) sadd = sd[t] - v;   // exclusive prefix at b (b < 196 <= 255)
    __syncthreads();
    const int add = sadd;

    const int kbase = b * BKEYS;
    for (int i = t; i < BKEYS; i += 256) {
        int k = kbase + i;
        int o = ((k < NR) ? offs[k] : 0) + add;
        obase[i] = o;
        cur[i] = 0;
        if (k < NR) offs[k] = o;    // finalize for k_fused
    }
    if (b == 0 && t == 0) offs[NR] = N_EDGES;
    __syncthreads();

    const int n = gcur[b];
    const uint2* rec = gbin + (size_t)b * BCAP;
    for (int j = t; j < n; j += 256) {
        uint2 r = rec[j];
        int li = r.y - kbase;
        int sub = atomicAdd(&cur[li], 1);
        srcS[obase[li] + sub] = (int)r.x;
    }
}

// ---------------- converts (cvt_x + wprep + gcur-zero fused) ----------------

#define W1_ELEMS (9 * 128 * 128)   // NBt=8
#define W2_ELEMS (9 * 64 * 128)    // NBt=4
#define N4       (N_NODES * 32)    // 1.6M float4 groups

__global__ __launch_bounds__(256) void k_cvtw(
    const float* __restrict__ x, unsigned short* __restrict__ xb,
    const float* __restrict__ root1, const float* __restrict__ W1,
    const float* __restrict__ root2, const float* __restrict__ W2,
    unsigned short* __restrict__ Wt1, unsigned short* __restrict__ Wt2,
    int* __restrict__ gcur)
{
    const int idx = blockIdx.x * 256 + threadIdx.x;
    if (blockIdx.x == 0) gcur[threadIdx.x] = 0;
    if (idx < N4) {
        float4 v = *(const float4*)(x + (size_t)idx * 4);
        ushort4 o;
        o.x = f2bf(v.x); o.y = f2bf(v.y); o.z = f2bf(v.z); o.w = f2bf(v.w);
        *(ushort4*)(xb + (size_t)idx * 4) = o;
    }
    if (idx < W1_ELEMS) {
        int j    = idx & 7;
        int lane = (idx >> 3) & 63;
        int r    = idx >> 9;
        int nb   = r & 7;        // NBt = 8
        int r2   = r >> 3;
        int kk   = r2 & 3;
        int seg  = r2 >> 2;
        int k = kk * 32 + (lane >> 4) * 8 + j;
        int n = nb * 16 + (lane & 15);
        float v = (seg == 0) ? root1[k * 128 + n] : W1[((seg - 1) * 128 + k) * 128 + n];
        Wt1[idx] = f2bf(v);
    } else if (idx < W1_ELEMS + W2_ELEMS) {
        int i2   = idx - W1_ELEMS;
        int j    = i2 & 7;
        int lane = (i2 >> 3) & 63;
        int r    = i2 >> 9;
        int nb   = r & 3;        // NBt = 4
        int r2   = r >> 2;
        int kk   = r2 & 3;
        int seg  = r2 >> 2;
        int k = kk * 32 + (lane >> 4) * 8 + j;
        int n = nb * 16 + (lane & 15);
        float v = (seg == 0) ? root2[k * 64 + n] : W2[((seg - 1) * 128 + k) * 64 + n];
        Wt2[i2] = f2bf(v);
    }
}

// ---------------- fused gather + MFMA layer ----------------
// Block = 1024 threads (16 waves), 16-node tile, 3125 blocks.
// Gather thread = (node, rel, oct-of-16-feats): 8 threads share a chain, each
// edge costs a thread only 2x16B loads -> 4-edge-ILP loop fits in ~70 VGPR
// (8 loads in flight vs the old effective 4), straggler rounds ceil(deg/4).
// Each wave-load = 8 fully-contiguous 256B rows (8 chains x 8 octs).
// LDS A-slabs swizzled per-relation at 16B granules (g ^= rel): rel stride
// 1088 words == 0 mod 32 made gather writes 2-way-conflicted (6.1M cycles);
// XOR makes write banks even; MFMA read un-XORs (uniform per instr, free).
// One barrier; MFMA with fragment-ordered B. FOUT=128: waves 0-7 own col-tiles,
// 8-15 retire; FOUT=64: waves 0-3.

template <int FOUT, bool RELU, bool OUT_BF16>
__global__ __launch_bounds__(1024, 4) void k_fused(
    const unsigned short* __restrict__ xin,  // [N,128] bf16
    const unsigned short* __restrict__ WtP,  // fragment-ordered weights
    const float* __restrict__ bias,          // [FOUT]
    const int* __restrict__ offs,            // [NR+1]
    const int* __restrict__ srcS,            // [E]
    unsigned short* __restrict__ outb,       // [N,FOUT] bf16 (if OUT_BF16)
    float* __restrict__ outf)                // [N,FOUT] fp32 (else)
{
    constexpr int NBt = FOUT / 16;           // 8 (L1) / 4 (L2)
    __shared__ __align__(16) unsigned short As[9][16][136];  // 39.2 KB

    const int t = threadIdx.x;
    const int node0 = blockIdx.x * 16;

    // ---- seg-0 staging: threads 0-127, coalesced (granules 2sp,2sp+1, s=0) ----
    if (t < 128) {
        const int sr = t >> 3;
        const int sp = t & 7;
        const uint4* src = (const uint4*)(xin + (size_t)(node0 + sr) * 128 + sp * 16);
        uint4 r0 = src[0], r1 = src[1];
        uint4* d = (uint4*)&As[0][sr][sp * 16];
        d[0] = r0; d[1] = r1;
    }

    // ---- gather: 8 threads per chain (node, rel, oct), 4-edge ILP ----
    {
        const int oct = t & 7;         // 16-feat slice
        const int rel = (t >> 3) & 7;  // relation
        const int nl  = t >> 6;        // local node 0..15

        const int pair = (node0 + nl) * 8 + rel;
        const int beg = offs[pair];
        const int end = offs[pair + 1];
        const int deg = end - beg;

        const unsigned short* bx = xin + oct * 16;
        float a[16];
#pragma unroll
        for (int i = 0; i < 16; ++i) a[i] = 0.f;

        int j = beg;
        for (; j + 3 < end; j += 4) {
            int s0 = srcS[j], s1 = srcS[j + 1], s2 = srcS[j + 2], s3 = srcS[j + 3];
            const uint4* p0 = (const uint4*)(bx + (size_t)s0 * 128);
            const uint4* p1 = (const uint4*)(bx + (size_t)s1 * 128);
            const uint4* p2 = (const uint4*)(bx + (size_t)s2 * 128);
            const uint4* p3 = (const uint4*)(bx + (size_t)s3 * 128);
            uint4 u0 = p0[0], u1 = p0[1];
            uint4 u2 = p1[0], u3 = p1[1];
            uint4 u4 = p2[0], u5 = p2[1];
            uint4 u6 = p3[0], u7 = p3[1];
            acc16(a, u0, u1);
            acc16(a, u2, u3);
            acc16(a, u4, u5);
            acc16(a, u6, u7);
        }
        if (j + 1 < end) {
            int s0 = srcS[j], s1 = srcS[j + 1];
            const uint4* p0 = (const uint4*)(bx + (size_t)s0 * 128);
            const uint4* p1 = (const uint4*)(bx + (size_t)s1 * 128);
            uint4 u0 = p0[0], u1 = p0[1];
            uint4 u2 = p1[0], u3 = p1[1];
            acc16(a, u0, u1);
            acc16(a, u2, u3);
            j += 2;
        }
        if (j < end) {
            int s0 = srcS[j];
            const uint4* p0 = (const uint4*)(bx + (size_t)s0 * 128);
            uint4 u0 = p0[0], u1 = p0[1];
            acc16(a, u0, u1);
        }

        float scl = 1.f / (float)(deg > 1 ? deg : 1);
        unsigned int pk[8];
#pragma unroll
        for (int i = 0; i < 8; ++i)
            pk[i] = (unsigned int)f2bf(a[i * 2] * scl) |
                    ((unsigned int)f2bf(a[i * 2 + 1] * scl) << 16);
        uint4* G = (uint4*)&As[1 + rel][nl][0];
        const int g0 = oct * 2;
        G[g0 ^ rel]       = make_uint4(pk[0], pk[1], pk[2], pk[3]);
        G[(g0 + 1) ^ rel] = make_uint4(pk[4], pk[5], pk[6], pk[7]);
    }

    __syncthreads();   // all 9 As slabs ready (the only barrier)

    // ---- MFMA phase: wave w owns col-tile w ----
    const int lane = t & 63;
    const int w = t >> 6;
    if (w >= NBt) return;            // extra waves done (no barriers after)
    const int quad = lane >> 4;
    const int tc = lane & 15;

    f32x4 acc = (f32x4){0.f, 0.f, 0.f, 0.f};
    const bf16x8* Bp = (const bf16x8*)WtP;

#pragma unroll
    for (int seg = 0; seg < 9; ++seg) {
        const uint4* Ag = (const uint4*)&As[seg][tc][0];
        const int s = (seg == 0) ? 0 : (seg - 1);   // un-swizzle
#pragma unroll
        for (int kk = 0; kk < 4; ++kk) {
            bf16x8 af = *(const bf16x8*)(Ag + (((kk << 2) + quad) ^ s));
            bf16x8 bf = Bp[((seg * 4 + kk) * NBt + w) * 64 + lane];
            acc = __builtin_amdgcn_mfma_f32_16x16x32_bf16(af, bf, acc, 0, 0, 0);
        }
    }

    // epilogue: D layout col = lane&15, row = quad*4 + reg
    const int col = w * 16 + tc;
    const float bs = bias[col];
#pragma unroll
    for (int i = 0; i < 4; ++i) {
        int r = node0 + quad * 4 + i;
        float v = acc[i] + bs;
        if (RELU) v = fmaxf(v, 0.f);
        if (OUT_BF16) outb[(size_t)r * FOUT + col] = f2bf(v);
        else          outf[(size_t)r * FOUT + col] = v;
    }
}

// ---------------- launch ----------------

extern "C" void kernel_launch(void* const* d_in, const int* in_sizes, int n_in,
                              void* d_out, int out_size, void* d_ws, size_t ws_size,
                              hipStream_t stream) {
    const float* x     = (const float*)d_in[0];
    const int*   ei    = (const int*)d_in[1];  // [2][E]: row0=src, row1=dst
    const int*   et    = (const int*)d_in[2];  // [E]
    const float* W1    = (const float*)d_in[3];
    const float* root1 = (const float*)d_in[4];
    const float* b1    = (const float*)d_in[5];
    const float* W2    = (const float*)d_in[6];
    const float* root2 = (const float*)d_in[7];
    const float* b2    = (const float*)d_in[8];
    float* out = (float*)d_out;

    int* ws     = (int*)d_ws;
    int* cnt    = ws;                  // NR        (region reused for Wt1)
    int* offs   = cnt + NR;            // NR+128
    int* wt2buf = offs + NR + 128;     // NR        (holds Wt2, 144 KB)
    int* bsum   = wt2buf + NR;         // 256
    int* bsum2  = bsum + 256;          // 256 (unused, kept for layout)
    int* gcur   = bsum2 + 256;         // 256
    int* srcS   = gcur + 256;          // E
    unsigned short* xb  = (unsigned short*)(srcS + N_EDGES); // [N,128] bf16 (12.8 MB)
    unsigned short* hb  = xb + (size_t)N_NODES * 128;        // [N,128] bf16 (12.8 MB)
    uint2* gbin = (uint2*)(hb + (size_t)N_NODES * 128);      // 8.03 MB
    unsigned short* Wt1 = (unsigned short*)cnt;
    unsigned short* Wt2 = (unsigned short*)wt2buf;
    // total ws usage: ~8 MB ints + 12.8 + 12.8 + 8 = ~42 MB (ws = 256 MiB)

    // 6 dispatches total (was 11): cvt/wprep/gcur-zero fused; scan1 fused into
    // bcount; scan2+scan3 fused into bscat.
    k_cvtw<<<(N4 + 255) / 256, 256, 0, stream>>>(x, xb, root1, W1, root2, W2,
                                                 Wt1, Wt2, gcur);
    k_binA<<<BINBLK, 256, 0, stream>>>(ei, ei + N_EDGES, et, gcur, gbin);
    k_bcount_scan<<<NBKT, 256, 0, stream>>>(gcur, gbin, offs, bsum);
    k_bscat_final<<<NBKT, 256, 0, stream>>>(gcur, gbin, bsum, offs, srcS);

    const int NT = N_NODES / 16;  // 3125 exactly

    k_fused<128, true,  true ><<<NT, 1024, 0, stream>>>(xb, Wt1, b1, offs, srcS, hb, nullptr);
    k_fused<64,  false, false><<<NT, 1024, 0, stream>>>(hb, Wt2, b2, offs, srcS, nullptr, out);
}

// Round 2
// 250.669 us; speedup vs baseline: 1.1503x; 1.1503x over previous
//
#include <hip/hip_runtime.h>

#define N_NODES 50000
#define N_EDGES 800000
#define R_REL   8
#define NR      (N_NODES * R_REL)        // 400000

// bucketed CSR build
#define NBKT    196                      // buckets of 256 dst-nodes
#define BNSH    8                        // dst>>8 -> bucket
#define BKEYS   2048                     // keys per bucket (256 nodes x 8 rels)
#define BCAP    5120                     // record capacity per bucket (mean 4083, +16 sigma)
#define SLAB    2048                     // edges per bin-block
#define BINBLK  ((N_EDGES + SLAB - 1) / SLAB)  // 391

typedef float  f32x4  __attribute__((ext_vector_type(4)));
typedef __bf16 bf16x8 __attribute__((ext_vector_type(8)));

__device__ __forceinline__ unsigned short f2bf(float f) {
    unsigned int u = __float_as_uint(f);
    u = (u + 0x7FFFu + ((u >> 16) & 1u)) >> 16;   // RNE
    return (unsigned short)u;
}
__device__ __forceinline__ float bflo(unsigned int u) { return __uint_as_float(u << 16); }
__device__ __forceinline__ float bfhi(unsigned int u) { return __uint_as_float(u & 0xFFFF0000u); }

__device__ __forceinline__ void acc16(float* a, uint4 u0, uint4 u1) {
    a[0]  += bflo(u0.x);   a[1]  += bfhi(u0.x);
    a[2]  += bflo(u0.y);   a[3]  += bfhi(u0.y);
    a[4]  += bflo(u0.z);   a[5]  += bfhi(u0.z);
    a[6]  += bflo(u0.w);   a[7]  += bfhi(u0.w);
    a[8]  += bflo(u1.x);   a[9]  += bfhi(u1.x);
    a[10] += bflo(u1.y);   a[11] += bfhi(u1.y);
    a[12] += bflo(u1.z);   a[13] += bfhi(u1.z);
    a[14] += bflo(u1.w);   a[15] += bfhi(u1.w);
}

// ---------------- bucketed CSR build ----------------

__global__ __launch_bounds__(256) void k_binA(
    const int* __restrict__ src, const int* __restrict__ dst,
    const int* __restrict__ et, int* __restrict__ gcur,
    uint2* __restrict__ gbin)
{
    __shared__ int hist[NBKT];
    __shared__ int base[NBKT];
    const int t = threadIdx.x;
    const int e0 = blockIdx.x * SLAB;
    for (int i = t; i < NBKT; i += 256) hist[i] = 0;
    __syncthreads();
#pragma unroll
    for (int i = 0; i < SLAB / 256; ++i) {
        int e = e0 + i * 256 + t;
        if (e < N_EDGES) atomicAdd(&hist[dst[e] >> BNSH], 1);
    }
    __syncthreads();
    for (int i = t; i < NBKT; i += 256) {
        int h = hist[i];
        base[i] = (h > 0) ? atomicAdd(&gcur[i], h) : 0;
        hist[i] = 0;   // reuse as sub-cursor
    }
    __syncthreads();
#pragma unroll
    for (int i = 0; i < SLAB / 256; ++i) {
        int e = e0 + i * 256 + t;
        if (e < N_EDGES) {
            int d = dst[e];
            int b = d >> BNSH;
            int sub = atomicAdd(&hist[b], 1);
            gbin[b * BCAP + base[b] + sub] =
                make_uint2((unsigned)src[e], (unsigned)(d * 8 + et[e]));
        }
    }
}

// count + in-block exclusive scan (bucket b's 2048 keys == scan chunk b).
// Writes PARTIAL offs (missing inter-bucket prefix) + bsum[b] = bucket total.
__global__ __launch_bounds__(256) void k_bcount_scan(
    const int* __restrict__ gcur, const uint2* __restrict__ gbin,
    int* __restrict__ offs, int* __restrict__ bsum)
{
    __shared__ int lc[BKEYS];
    __shared__ int sd[256];
    const int t = threadIdx.x;
    const int b = blockIdx.x;
    for (int i = t; i < BKEYS; i += 256) lc[i] = 0;
    __syncthreads();
    const int n = gcur[b];
    const uint2* rec = gbin + (size_t)b * BCAP;
    const int kbase = b * BKEYS;
    for (int j = t; j < n; j += 256)
        atomicAdd(&lc[rec[j].y - kbase], 1);
    __syncthreads();
    // 8-per-thread serial scan + 256-wide block scan
    const int base = t * 8;
    int v[8];
    int tot = 0;
#pragma unroll
    for (int i = 0; i < 8; i++) {
        int xv = lc[base + i];
        v[i] = tot;
        tot += xv;
    }
    sd[t] = tot;
    __syncthreads();
    for (int off = 1; off < 256; off <<= 1) {
        int y = (t >= off) ? sd[t - off] : 0;
        __syncthreads();
        sd[t] += y;
        __syncthreads();
    }
    int excl = sd[t] - tot;
#pragma unroll
    for (int i = 0; i < 8; i++) {
        int k = kbase + base + i;
        if (k < NR) offs[k] = v[i] + excl;
    }
    if (t == 255) bsum[b] = sd[255];
}

// inline 196-entry scan of bsum (every block redoes it, trivial) ->
// finalize this bucket's offs slice -> scatter srcS from LDS bases.
__global__ __launch_bounds__(256) void k_bscat_final(
    const int* __restrict__ gcur, const uint2* __restrict__ gbin,
    const int* __restrict__ bsum, int* __restrict__ offs,
    int* __restrict__ srcS)
{
    __shared__ int obase[BKEYS];
    __shared__ int cur[BKEYS];
    __shared__ int sd[256];
    __shared__ int sadd;
    const int t = threadIdx.x;
    const int b = blockIdx.x;

    int v = (t < NBKT) ? bsum[t] : 0;
    sd[t] = v;
    __syncthreads();
    for (int off = 1; off < 256; off <<= 1) {
        int y = (t >= off) ? sd[t - off] : 0;
        __syncthreads();
        sd[t] += y;
        __syncthreads();
    }
    if (t == b) sadd = sd[t] - v;   // exclusive prefix at b (b < 196 <= 255)
    __syncthreads();
    const int add = sadd;

    const int kbase = b * BKEYS;
    for (int i = t; i < BKEYS; i += 256) {
        int k = kbase + i;
        int o = ((k < NR) ? offs[k] : 0) + add;
        obase[i] = o;
        cur[i] = 0;
        if (k < NR) offs[k] = o;    // finalize for k_fused
    }
    if (b == 0 && t == 0) offs[NR] = N_EDGES;
    __syncthreads();

    const int n = gcur[b];
    const uint2* rec = gbin + (size_t)b * BCAP;
    for (int j = t; j < n; j += 256) {
        uint2 r = rec[j];
        int li = r.y - kbase;
        int sub = atomicAdd(&cur[li], 1);
        srcS[obase[li] + sub] = (int)r.x;
    }
}

// ---------------- converts (cvt_x + wprep + gcur-zero fused) ----------------

#define W1_ELEMS (9 * 128 * 128)   // NBt=8
#define W2_ELEMS (9 * 64 * 128)    // NBt=4
#define N4       (N_NODES * 32)    // 1.6M float4 groups

__global__ __launch_bounds__(256) void k_cvtw(
    const float* __restrict__ x, unsigned short* __restrict__ xb,
    const float* __restrict__ root1, const float* __restrict__ W1,
    const float* __restrict__ root2, const float* __restrict__ W2,
    unsigned short* __restrict__ Wt1, unsigned short* __restrict__ Wt2,
    int* __restrict__ gcur)
{
    const int idx = blockIdx.x * 256 + threadIdx.x;
    if (blockIdx.x == 0) gcur[threadIdx.x] = 0;
    if (idx < N4) {
        float4 v = *(const float4*)(x + (size_t)idx * 4);
        ushort4 o;
        o.x = f2bf(v.x); o.y = f2bf(v.y); o.z = f2bf(v.z); o.w = f2bf(v.w);
        *(ushort4*)(xb + (size_t)idx * 4) = o;
    }
    if (idx < W1_ELEMS) {
        int j    = idx & 7;
        int lane = (idx >> 3) & 63;
        int r    = idx >> 9;
        int nb   = r & 7;        // NBt = 8
        int r2   = r >> 3;
        int kk   = r2 & 3;
        int seg  = r2 >> 2;
        int k = kk * 32 + (lane >> 4) * 8 + j;
        int n = nb * 16 + (lane & 15);
        float v = (seg == 0) ? root1[k * 128 + n] : W1[((seg - 1) * 128 + k) * 128 + n];
        Wt1[idx] = f2bf(v);
    } else if (idx < W1_ELEMS + W2_ELEMS) {
        int i2   = idx - W1_ELEMS;
        int j    = i2 & 7;
        int lane = (i2 >> 3) & 63;
        int r    = i2 >> 9;
        int nb   = r & 3;        // NBt = 4
        int r2   = r >> 2;
        int kk   = r2 & 3;
        int seg  = r2 >> 2;
        int k = kk * 32 + (lane >> 4) * 8 + j;
        int n = nb * 16 + (lane & 15);
        float v = (seg == 0) ? root2[k * 64 + n] : W2[((seg - 1) * 128 + k) * 64 + n];
        Wt2[i2] = f2bf(v);
    }
}

// ---------------- fused gather + MFMA layer ----------------
// Block = 512 threads (8 waves), 16-node tile, 3125 blocks exact.
// Gather mapping = round-0's proven structure: thread = (node, rel, 32-feat
// quarter), 4 lanes/chain, 4x uint4 per edge, 2-edge ILP (8 uint4 in flight
// per lane on the main path). Round-1's octet mapping halved per-lane
// outstanding bytes for typical deg<=2 chains and cost 23% BW -- the gather
// is MLP/latency-bound, per-lane in-flight loads are the currency.
// NEW vs round-0: LDS A-slab writes XOR-swizzled at 16B granules (g ^= rel).
// Un-swizzled, rel-stride = 272 granules = 0 mod 8, so 16 lanes/instr hit one
// 4-bank group (2-way conflict, 6.1M cycles). With ^rel: 8 lanes/group =
// conflict-free (exact 8-phase minimum). MFMA read un-XORs with the
// instruction-uniform constant (seg-1) -- read stays conflict-free.
// One barrier; fragment-ordered B (1 coalesced txn per B-frag).
// FOUT=128: wave w owns col-tile w. FOUT=64: waves 4-7 retire after barrier.

template <int FOUT, bool RELU, bool OUT_BF16>
__global__ __launch_bounds__(512) void k_fused(
    const unsigned short* __restrict__ xin,  // [N,128] bf16
    const unsigned short* __restrict__ WtP,  // fragment-ordered weights
    const float* __restrict__ bias,          // [FOUT]
    const int* __restrict__ offs,            // [NR+1]
    const int* __restrict__ srcS,            // [E]
    unsigned short* __restrict__ outb,       // [N,FOUT] bf16 (if OUT_BF16)
    float* __restrict__ outf)                // [N,FOUT] fp32 (else)
{
    constexpr int NBt = FOUT / 16;           // 8 (L1) / 4 (L2)
    __shared__ __align__(16) unsigned short As[9][16][136];  // 39.2 KB

    const int t = threadIdx.x;
    const int node0 = blockIdx.x * 16;

    // ---- seg-0 staging: threads 0-127, coalesced (already conflict-free:
    //      granule = sr*17 + 2*sp + i -> 8 lanes per bank group) ----
    if (t < 128) {
        const int sr = t >> 3;
        const int sp = t & 7;
        const uint4* src = (const uint4*)(xin + (size_t)(node0 + sr) * 128 + sp * 16);
        uint4 r0 = src[0], r1 = src[1];
        uint4* d = (uint4*)&As[0][sr][sp * 16];
        d[0] = r0; d[1] = r1;
    }

    // ---- gather: one chain per (node, rel), 4 lanes (32-feat quarters) ----
    {
        const int nl  = t >> 5;        // local node 0..15
        const int rel = (t >> 2) & 7;  // relation
        const int q   = t & 3;         // 32-feat quarter

        const int pair = (node0 + nl) * 8 + rel;
        const int beg = offs[pair];
        const int end = offs[pair + 1];
        const int deg = end - beg;

        const unsigned short* bx = xin + q * 32;
        float a[32];
#pragma unroll
        for (int i = 0; i < 32; ++i) a[i] = 0.f;

        int j = beg;
        for (; j + 1 < end; j += 2) {
            int s0 = srcS[j];
            int s1 = srcS[j + 1];
            const uint4* p0 = (const uint4*)(bx + (size_t)s0 * 128);
            const uint4* p1 = (const uint4*)(bx + (size_t)s1 * 128);
            uint4 v0 = p0[0], v1 = p0[1], v2 = p0[2], v3 = p0[3];
            uint4 w0 = p1[0], w1 = p1[1], w2 = p1[2], w3 = p1[3];
            acc16(a, v0, v1);
            acc16(a + 16, v2, v3);
            acc16(a, w0, w1);
            acc16(a + 16, w2, w3);
        }
        if (j < end) {
            int s = srcS[j];
            const uint4* p = (const uint4*)(bx + (size_t)s * 128);
            uint4 v0 = p[0], v1 = p[1], v2 = p[2], v3 = p[3];
            acc16(a, v0, v1);
            acc16(a + 16, v2, v3);
        }

        float scl = 1.f / (float)(deg > 1 ? deg : 1);
        unsigned int pk[16];
#pragma unroll
        for (int i = 0; i < 16; ++i)
            pk[i] = (unsigned int)f2bf(a[i * 2] * scl) |
                    ((unsigned int)f2bf(a[i * 2 + 1] * scl) << 16);
        // swizzled stores: row-local granule (q*4+i) ^ rel, i=0..3
        uint4* G = (uint4*)&As[1 + rel][nl][0];
        const int g0 = q * 4;
        G[(g0 + 0) ^ rel] = make_uint4(pk[0],  pk[1],  pk[2],  pk[3]);
        G[(g0 + 1) ^ rel] = make_uint4(pk[4],  pk[5],  pk[6],  pk[7]);
        G[(g0 + 2) ^ rel] = make_uint4(pk[8],  pk[9],  pk[10], pk[11]);
        G[(g0 + 3) ^ rel] = make_uint4(pk[12], pk[13], pk[14], pk[15]);
    }

    __syncthreads();   // all 9 As slabs ready (the only barrier)

    // ---- MFMA phase: wave w owns col-tile w ----
    const int lane = t & 63;
    const int w = t >> 6;
    if (w >= NBt) return;            // FOUT=64: waves 4-7 done (no barriers after)
    const int quad = lane >> 4;
    const int tc = lane & 15;

    f32x4 acc = (f32x4){0.f, 0.f, 0.f, 0.f};
    const bf16x8* Bp = (const bf16x8*)WtP;

#pragma unroll
    for (int seg = 0; seg < 9; ++seg) {
        const uint4* Ag = (const uint4*)&As[seg][tc][0];
        const int s = (seg == 0) ? 0 : (seg - 1);   // un-swizzle (uniform per instr)
#pragma unroll
        for (int kk = 0; kk < 4; ++kk) {
            bf16x8 af = *(const bf16x8*)(Ag + (((kk << 2) + quad) ^ s));
            bf16x8 bf = Bp[((seg * 4 + kk) * NBt + w) * 64 + lane];
            acc = __builtin_amdgcn_mfma_f32_16x16x32_bf16(af, bf, acc, 0, 0, 0);
        }
    }

    // epilogue: D layout col = lane&15, row = quad*4 + reg
    const int col = w * 16 + tc;
    const float bs = bias[col];
#pragma unroll
    for (int i = 0; i < 4; ++i) {
        int r = node0 + quad * 4 + i;
        float v = acc[i] + bs;
        if (RELU) v = fmaxf(v, 0.f);
        if (OUT_BF16) outb[(size_t)r * FOUT + col] = f2bf(v);
        else          outf[(size_t)r * FOUT + col] = v;
    }
}

// ---------------- launch ----------------

extern "C" void kernel_launch(void* const* d_in, const int* in_sizes, int n_in,
                              void* d_out, int out_size, void* d_ws, size_t ws_size,
                              hipStream_t stream) {
    const float* x     = (const float*)d_in[0];
    const int*   ei    = (const int*)d_in[1];  // [2][E]: row0=src, row1=dst
    const int*   et    = (const int*)d_in[2];  // [E]
    const float* W1    = (const float*)d_in[3];
    const float* root1 = (const float*)d_in[4];
    const float* b1    = (const float*)d_in[5];
    const float* W2    = (const float*)d_in[6];
    const float* root2 = (const float*)d_in[7];
    const float* b2    = (const float*)d_in[8];
    float* out = (float*)d_out;

    int* ws     = (int*)d_ws;
    int* cnt    = ws;                  // NR        (region reused for Wt1)
    int* offs   = cnt + NR;            // NR+128
    int* wt2buf = offs + NR + 128;     // NR        (holds Wt2, 144 KB)
    int* bsum   = wt2buf + NR;         // 256
    int* bsum2  = bsum + 256;          // 256 (unused, kept for layout)
    int* gcur   = bsum2 + 256;         // 256
    int* srcS   = gcur + 256;          // E
    unsigned short* xb  = (unsigned short*)(srcS + N_EDGES); // [N,128] bf16 (12.8 MB)
    unsigned short* hb  = xb + (size_t)N_NODES * 128;        // [N,128] bf16 (12.8 MB)
    uint2* gbin = (uint2*)(hb + (size_t)N_NODES * 128);      // 8.03 MB
    unsigned short* Wt1 = (unsigned short*)cnt;
    unsigned short* Wt2 = (unsigned short*)wt2buf;
    // total ws usage: ~8 MB ints + 12.8 + 12.8 + 8 = ~42 MB (ws = 256 MiB)

    // 6 dispatches total: cvt/wprep/gcur-zero fused; scan1 fused into bcount;
    // scan2+scan3 fused into bscat.
    k_cvtw<<<(N4 + 255) / 256, 256, 0, stream>>>(x, xb, root1, W1, root2, W2,
                                                 Wt1, Wt2, gcur);
    k_binA<<<BINBLK, 256, 0, stream>>>(ei, ei + N_EDGES, et, gcur, gbin);
    k_bcount_scan<<<NBKT, 256, 0, stream>>>(gcur, gbin, offs, bsum);
    k_bscat_final<<<NBKT, 256, 0, stream>>>(gcur, gbin, bsum, offs, srcS);

    const int NT = N_NODES / 16;  // 3125 exactly

    k_fused<128, true,  true ><<<NT, 512, 0, stream>>>(xb, Wt1, b1, offs, srcS, hb, nullptr);
    k_fused<64,  false, false><<<NT, 512, 0, stream>>>(hb, Wt2, b2, offs, srcS, nullptr, out);
}